// Round 16
// baseline (49.156 us; speedup 1.0000x reference)
//
#include <hip/hip_runtime.h>

#define CIN  128
#define CHUNKF 32768       // HW*T floats per (n, channel)

typedef float f32x4 __attribute__((ext_vector_type(4)));
typedef short s16x8 __attribute__((ext_vector_type(8)));

// ws float layout (main path):
// [0,4096)       qw1 f32 [32 o1][128 c]
// [4096,8192)    qw2 f32 [128 o2][32 j]
// [8192,12288)   msumP [32 slot][128 c] (atomic partials)
// [12288]        done counter (uint)
// [12544,14592)  qw1bf ushort[32][128]
// [14592,16640)  qw2bf ushort[128][32]
// Fallback path (r12): msum at 8192(128), qw1bf at 8448, qw2bf at 10496.

__device__ __forceinline__ uint pack_hilo(float f) {
  uint b = __float_as_uint(f);
  uint hi = b & 0xffff0000u;
  float lo = f - __uint_as_float(hi);
  return (hi >> 16) | (__float_as_uint(lo) & 0xffff0000u);
}

// ===================== MAIN PATH =====================
// weights + zero msumP/counter. 160 blocks x 128 thr.
__global__ __launch_bounds__(128) void wnorm_init(
    const float* __restrict__ v1, const float* __restrict__ g1,
    const float* __restrict__ v2, const float* __restrict__ g2,
    float* __restrict__ ws) {
  int b = blockIdx.x, tid = threadIdx.x;
  if (b < 32) ws[8192 + b * 128 + tid] = 0.f;            // msumP
  if (b == 32 && tid == 0) *(uint*)(ws + 12288) = 0u;    // done counter
  bool first = (b < 32);
  int row = first ? b : b - 32;
  int len = first ? 128 : 32;
  const float* v = first ? v1 : v2;
  const float* g = first ? g1 : g2;

  double val = 0.0;
  if (tid < len) { double t = (double)v[row * len + tid]; val = t * t; }
  for (int off = 32; off >= 1; off >>= 1) val += __shfl_down(val, off);
  __shared__ double partial[2];
  if ((tid & 63) == 0) partial[tid >> 6] = val;
  __syncthreads();
  double norm = sqrt(partial[0] + partial[1]);
  if (tid < len) {
    double w = (double)g[row] * (double)v[row * len + tid] / norm;
    double qd = rint(w * 32.0) * 0.03125;        // step 2/64, round-half-even
    qd = fmin(fmax(qd, -2.0), 1.984375);
    float qf = (float)qd;                        // bf16-exact
    ushort bf = (ushort)(__float_as_uint(qf) >> 16);
    if (first) {
      ws[row * 128 + tid] = qf;                            // qw1 f32
      ((ushort*)(ws + 12544))[row * 128 + tid] = bf;       // qw1bf
    } else {
      ws[4096 + row * 32 + tid] = qf;                      // qw2 f32
      ((ushort*)(ws + 14592))[row * 32 + tid] = bf;        // qw2bf
    }
  }
}

// Single-read main kernel: x loaded ONCE; mean partials computed during the
// staging pass (half to LDS, half held in regs); MFMA pipeline; spin+kappa
// only before epilogue. 1024 blocks x 256 thr, 4 blocks/CU (host-gated).
__global__ __launch_bounds__(256, 4) void fused_main(
    const float* __restrict__ x, float* __restrict__ ws,
    float* __restrict__ out) {
  const ushort* qw1bf = (const ushort*)(ws + 12544);
  const ushort* qw2bf = (const ushort*)(ws + 14592);

  __shared__ uint xs[8192];     // 32 KB; z overlays after barrier
  __shared__ float mls[128];
  __shared__ float zred[288];
  __shared__ float kls[128];

  const int tid = threadIdx.x;
  const int wv = tid >> 6;
  const int l  = tid & 63;
  const int g  = l >> 4;
  const int ln = l & 15;

  const int nb  = blockIdx.x >> 8;
  const int hw0 = (blockIdx.x & 255) * 4;
  const float* xblk = x + (size_t)nb * CIN * CHUNKF + (size_t)hw0 * 32;
  float* msumP = ws + 8192;

  const int l31 = tid & 31;
  const int cg  = tid >> 5;              // channel sub-index within an 8-group
  const int t0 = (l31 & 7) * 4;
  const float wt0 = (float)(32 - t0), wt1 = (float)(31 - t0);
  const float wt2 = (float)(30 - t0), wt3 = (float)(29 - t0);
  const int slot = blockIdx.x & 31;

  // ---- phase A / staging: single x read. Half 0 (c 0..63): reduce+pack+LDS.
  float4 xr[8];
#pragma unroll
  for (int k = 0; k < 8; ++k)
    xr[k] = *(const float4*)(xblk + (size_t)(k * 8 + cg) * CHUNKF + l31 * 4);
#pragma unroll
  for (int k = 0; k < 8; ++k) {
    int c = k * 8 + cg;
    float4 v = xr[k];
    float pv = v.x * wt0 + v.y * wt1 + v.z * wt2 + v.w * wt3;
    pv += __shfl_down(pv, 16, 32);
    pv += __shfl_down(pv, 8, 32);
    pv += __shfl_down(pv, 4, 32);
    pv += __shfl_down(pv, 2, 32);
    pv += __shfl_down(pv, 1, 32);
    if (l31 == 0) atomicAdd(&msumP[slot * 128 + c], pv);
    uint4 pk;
    pk.x = pack_hilo(v.x); pk.y = pack_hilo(v.y);
    pk.z = pack_hilo(v.z); pk.w = pack_hilo(v.w);
    int u = l31 ^ ((c >> 2) & 6);
    *(uint4*)&xs[c * 128 + u * 4] = pk;
  }
  // Half 1 (c 64..127): reduce+pack+HOLD in regs (32 VGPR).
#pragma unroll
  for (int k = 0; k < 8; ++k)
    xr[k] = *(const float4*)(xblk + (size_t)(64 + k * 8 + cg) * CHUNKF + l31 * 4);
  uint4 xp[8];
#pragma unroll
  for (int k = 0; k < 8; ++k) {
    int c = 64 + k * 8 + cg;
    float4 v = xr[k];
    float pv = v.x * wt0 + v.y * wt1 + v.z * wt2 + v.w * wt3;
    pv += __shfl_down(pv, 16, 32);
    pv += __shfl_down(pv, 8, 32);
    pv += __shfl_down(pv, 4, 32);
    pv += __shfl_down(pv, 2, 32);
    pv += __shfl_down(pv, 1, 32);
    if (l31 == 0) atomicAdd(&msumP[slot * 128 + c], pv);
    xp[k].x = pack_hilo(v.x); xp[k].y = pack_hilo(v.y);
    xp[k].z = pack_hilo(v.z); xp[k].w = pack_hilo(v.w);
  }
  __threadfence();               // my atomics visible device-wide
  __syncthreads();               // block done depositing; xs ph0 staged
  if (tid == 0) atomicAdd((uint*)(ws + 12288), 1u);

  // ---- weight fragments (L2-hot)
  s16x8 A1[2][4];
#pragma unroll
  for (int jt = 0; jt < 2; ++jt)
#pragma unroll
    for (int ks = 0; ks < 4; ++ks)
      A1[jt][ks] = *(const s16x8*)(qw1bf + (jt * 16 + ln) * 128 + ks * 32 + g * 8);

  f32x4 acc1[2][2];
#pragma unroll
  for (int a = 0; a < 2; ++a)
#pragma unroll
    for (int b = 0; b < 2; ++b) acc1[a][b] = (f32x4){0.f, 0.f, 0.f, 0.f};

  // ---- MFMA pipeline, ph0 from xs, ph1 staged from xp regs
#pragma unroll
  for (int ph = 0; ph < 2; ++ph) {
    if (ph == 1) {
      __syncthreads();           // all ph0 reads done before overwrite
#pragma unroll
      for (int k = 0; k < 8; ++k) {
        int c = k * 8 + cg;      // local row 0..63
        int u = l31 ^ ((c >> 2) & 6);
        *(uint4*)&xs[c * 128 + u * 4] = xp[k];
      }
      __syncthreads();
    }
#pragma unroll
    for (int kl = 0; kl < 2; ++kl) {
#pragma unroll
      for (int nt = 0; nt < 2; ++nt) {
        const int n = wv * 32 + nt * 16 + ln;
        const int base = (kl * 32 + g * 8) * 128;
        const int u = ((n >> 2) ^ (((kl * 32 + g * 8) >> 2) & 6)) * 4 + (n & 3);
        uint q0 = xs[base + 0 * 128 + u], q1 = xs[base + 1 * 128 + u];
        uint q2 = xs[base + 2 * 128 + u], q3 = xs[base + 3 * 128 + u];
        uint q4 = xs[base + 4 * 128 + u], q5 = xs[base + 5 * 128 + u];
        uint q6 = xs[base + 6 * 128 + u], q7 = xs[base + 7 * 128 + u];
        uint4 H, L;
        H.x = (q0 & 0xffffu) | (q1 << 16);  H.y = (q2 & 0xffffu) | (q3 << 16);
        H.z = (q4 & 0xffffu) | (q5 << 16);  H.w = (q6 & 0xffffu) | (q7 << 16);
        L.x = (q0 >> 16) | (q1 & 0xffff0000u); L.y = (q2 >> 16) | (q3 & 0xffff0000u);
        L.z = (q4 >> 16) | (q5 & 0xffff0000u); L.w = (q6 >> 16) | (q7 & 0xffff0000u);
        s16x8 Bh = __builtin_bit_cast(s16x8, H);
        s16x8 Bl = __builtin_bit_cast(s16x8, L);
#pragma unroll
        for (int jt = 0; jt < 2; ++jt) {
          acc1[jt][nt] = __builtin_amdgcn_mfma_f32_16x16x32_bf16(A1[jt][ph * 2 + kl], Bh, acc1[jt][nt], 0, 0, 0);
          acc1[jt][nt] = __builtin_amdgcn_mfma_f32_16x16x32_bf16(A1[jt][ph * 2 + kl], Bl, acc1[jt][nt], 0, 0, 0);
        }
      }
    }
  }
  __syncthreads();               // xs reads done before z overlay

  // ---- z -> wave-private slab overlaying xs
  uint* zw = xs + wv * 1024;
#pragma unroll
  for (int jt = 0; jt < 2; ++jt)
#pragma unroll
    for (int nt = 0; nt < 2; ++nt) {
      int n = nt * 16 + ln;
      int u = (jt * 4 + g) ^ (n & 7);
      uint4 pk;
      pk.x = pack_hilo(acc1[jt][nt][0]);
      pk.y = pack_hilo(acc1[jt][nt][1]);
      pk.z = pack_hilo(acc1[jt][nt][2]);
      pk.w = pack_hilo(acc1[jt][nt][3]);
      *(uint4*)&zw[n * 32 + u * 4] = pk;
    }

  s16x8 Ah[2], Al[2];
#pragma unroll
  for (int mt = 0; mt < 2; ++mt) {
    int n = mt * 16 + ln;
    int u0 = (2 * g) ^ (n & 7);
    int u1 = (2 * g + 1) ^ (n & 7);
    uint4 qa = *(const uint4*)&zw[n * 32 + u0 * 4];
    uint4 qb = *(const uint4*)&zw[n * 32 + u1 * 4];
    uint4 H, L;
    H.x = (qa.x & 0xffffu) | (qa.y << 16);  H.y = (qa.z & 0xffffu) | (qa.w << 16);
    H.z = (qb.x & 0xffffu) | (qb.y << 16);  H.w = (qb.z & 0xffffu) | (qb.w << 16);
    L.x = (qa.x >> 16) | (qa.y & 0xffff0000u); L.y = (qa.z >> 16) | (qa.w & 0xffff0000u);
    L.z = (qb.x >> 16) | (qb.y & 0xffff0000u); L.w = (qb.z >> 16) | (qb.w & 0xffff0000u);
    Ah[mt] = __builtin_bit_cast(s16x8, H);
    Al[mt] = __builtin_bit_cast(s16x8, L);
  }

  // ---- wait for all mean deposits (satisfied long ago in practice), kappa
  if (tid == 0) {
    const uint* dc = (const uint*)(ws + 12288);
    int guard = 0;
    while (__hip_atomic_load(dc, __ATOMIC_ACQUIRE, __HIP_MEMORY_SCOPE_AGENT) < 1024u
           && ++guard < 10000000) { }
  }
  __syncthreads();
  __threadfence();
  if (tid < 128) {
    float m = 0.f;
#pragma unroll
    for (int p = 0; p < 32; ++p)
      m += __hip_atomic_load(&msumP[p * 128 + tid], __ATOMIC_RELAXED,
                             __HIP_MEMORY_SCOPE_AGENT);
    mls[tid] = m * (1.0f / 131072.0f);
  }
  __syncthreads();
  {
    int j = tid & 31, grp = tid >> 5;
    const float* qr = ws + j * 128 + grp * 16;
    float pp = 0.f;
#pragma unroll
    for (int cc = 0; cc < 16; ++cc) pp += qr[cc] * mls[grp * 16 + cc];
    zred[j * 8 + grp] = pp;
  }
  __syncthreads();
  if (tid < 32) {
    float t = 0.f;
#pragma unroll
    for (int gg = 0; gg < 8; ++gg) t += zred[tid * 8 + gg];
    zred[256 + tid] = t;
  }
  __syncthreads();
  if (tid < 128) {
    const float* q2 = ws + 4096 + tid * 32;
    float kk = 0.f;
#pragma unroll 8
    for (int j = 0; j < 32; ++j) kk += q2[j] * zred[256 + j];
    kls[tid] = kk;
  }
  __syncthreads();

  // ---- stage 2 + epilogue (r12-proven)
  const size_t outbase = (size_t)nb * CIN * CHUNKF + (size_t)(hw0 + wv) * 32;
#pragma unroll 1
  for (int h = 0; h < 2; ++h) {
    s16x8 B2[4];
#pragma unroll
    for (int q = 0; q < 4; ++q)
      B2[q] = *(const s16x8*)(qw2bf + ((h * 4 + q) * 16 + ln) * 32 + g * 8);
    f32x4 acc2[4][2];
#pragma unroll
    for (int a = 0; a < 4; ++a)
#pragma unroll
      for (int b = 0; b < 2; ++b) acc2[a][b] = (f32x4){0.f, 0.f, 0.f, 0.f};
#pragma unroll
    for (int mt = 0; mt < 2; ++mt)
#pragma unroll
      for (int q = 0; q < 4; ++q) {
        acc2[q][mt] = __builtin_amdgcn_mfma_f32_16x16x32_bf16(Ah[mt], B2[q], acc2[q][mt], 0, 0, 0);
        acc2[q][mt] = __builtin_amdgcn_mfma_f32_16x16x32_bf16(Al[mt], B2[q], acc2[q][mt], 0, 0, 0);
      }
#pragma unroll
    for (int q = 0; q < 4; ++q) {
      const int nt = h * 4 + q;
      float c0[2], c1[2], c2[2], c3[2], base[2], Qi0 = 0.f;
#pragma unroll
      for (int mt = 0; mt < 2; ++mt) {
        c0[mt] = acc2[q][mt][0];
        c1[mt] = c0[mt] + acc2[q][mt][1];
        c2[mt] = c1[mt] + acc2[q][mt][2];
        c3[mt] = c2[mt] + acc2[q][mt][3];
        float Qi = c3[mt];
        float t1 = __shfl_up(Qi, 16); if (g >= 1) Qi += t1;
        float t2 = __shfl_up(Qi, 32); if (g >= 2) Qi += t2;
        base[mt] = Qi - c3[mt];
        if (mt == 0) Qi0 = Qi;
      }
      float S0tot = __shfl(Qi0, 48 + ln);
      base[1] += S0tot;
      const float kpp = kls[nt * 16 + ln];
      float* op = out + outbase + (size_t)(nt * 16 + ln) * CHUNKF;
#pragma unroll
      for (int mt = 0; mt < 2; ++mt) {
        float Bv = base[mt] - kpp;
        float prev = fminf(fmaxf(Bv, -6.f), 6.f);
        if (mt == 0 && g == 0) prev = 0.f;
        float A0 = fminf(fmaxf(Bv + c0[mt], -6.f), 6.f);
        float A1v = fminf(fmaxf(Bv + c1[mt], -6.f), 6.f);
        float A2v = fminf(fmaxf(Bv + c2[mt], -6.f), 6.f);
        float A3v = fminf(fmaxf(Bv + c3[mt], -6.f), 6.f);
        *(float4*)(op + mt * 16 + g * 4) =
            make_float4(A0 - prev, A1v - A0, A2v - A1v, A3v - A2v);
      }
    }
  }
}

// ===================== FALLBACK (r12-proven, verbatim) =====================
__global__ __launch_bounds__(256) void wnorm_mean_kernel(
    const float* __restrict__ x,
    const float* __restrict__ v1, const float* __restrict__ g1,
    const float* __restrict__ v2, const float* __restrict__ g2,
    float* __restrict__ ws) {
  int tid = threadIdx.x;
  if (blockIdx.x < 2048) {
    int b = blockIdx.x;
    int chunk = b >> 2, quarter = b & 3;
    int i = chunk & 127;
    const float4* xp = (const float4*)(x + (size_t)chunk * CHUNKF + (size_t)quarter * 8192);
    float acc = 0.f;
#pragma unroll
    for (int it = 0; it < 8; ++it) {
      int f4i = tid + 256 * it;
      float4 v = xp[f4i];
      int t0 = (4 * f4i) & 31;
      acc += v.x * (float)(32 - t0) + v.y * (float)(31 - t0)
           + v.z * (float)(30 - t0) + v.w * (float)(29 - t0);
    }
    for (int off = 32; off >= 1; off >>= 1) acc += __shfl_down(acc, off);
    __shared__ float part[4];
    if ((tid & 63) == 0) part[tid >> 6] = acc;
    __syncthreads();
    if (tid == 0) atomicAdd(&ws[8192 + i], part[0] + part[1] + part[2] + part[3]);
  } else {
    int b = blockIdx.x - 2048;
    bool first = (b < 32);
    int row = first ? b : b - 32;
    int len = first ? 128 : 32;
    const float* v = first ? v1 : v2;
    const float* g = first ? g1 : g2;
    double val = 0.0;
    if (tid < len) { double t = (double)v[row * len + tid]; val = t * t; }
    for (int off = 32; off >= 1; off >>= 1) val += __shfl_down(val, off);
    __shared__ double partial[4];
    if ((tid & 63) == 0) partial[tid >> 6] = val;
    __syncthreads();
    double norm = sqrt(partial[0] + partial[1]);
    if (tid < len) {
      double w = (double)g[row] * (double)v[row * len + tid] / norm;
      double qd = rint(w * 32.0) * 0.03125;
      qd = fmin(fmax(qd, -2.0), 1.984375);
      float qf = (float)qd;
      ushort bf = (ushort)(__float_as_uint(qf) >> 16);
      if (first) {
        ws[row * 128 + tid] = qf;
        ((ushort*)(ws + 8448))[row * 128 + tid] = bf;
      } else {
        ws[4096 + row * 32 + tid] = qf;
        ((ushort*)(ws + 10496))[row * 32 + tid] = bf;
      }
    }
  }
}

__global__ __launch_bounds__(256, 4) void fused_kernel(
    const float* __restrict__ x, const float* __restrict__ ws,
    float* __restrict__ out) {
  const ushort* qw1bf = (const ushort*)(ws + 8448);
  const ushort* qw2bf = (const ushort*)(ws + 10496);

  __shared__ uint xs[8192];
  __shared__ float zred[288];
  __shared__ float kls[128];

  const int tid = threadIdx.x;
  const int wv = tid >> 6;
  const int l  = tid & 63;
  const int g  = l >> 4;
  const int ln = l & 15;

  const int nb  = blockIdx.x >> 8;
  const int hw0 = (blockIdx.x & 255) * 4;
  const float* xblk = x + (size_t)nb * CIN * CHUNKF + (size_t)hw0 * 32;

  float4 xr[8];
#pragma unroll
  for (int k = 0; k < 8; ++k) {
    int f = k * 256 + tid, c = f >> 5, n4 = f & 31;
    xr[k] = *(const float4*)(xblk + (size_t)c * CHUNKF + n4 * 4);
  }

  s16x8 A1[2][4];
#pragma unroll
  for (int jt = 0; jt < 2; ++jt)
#pragma unroll
    for (int ks = 0; ks < 4; ++ks)
      A1[jt][ks] = *(const s16x8*)(qw1bf + (jt * 16 + ln) * 128 + ks * 32 + g * 8);

  {
    int j = tid & 31, grp = tid >> 5;
    const float* qr = ws + j * 128 + grp * 16;
    const float* mr = ws + 8192 + grp * 16;
    float pp = 0.f;
#pragma unroll
    for (int cc = 0; cc < 16; ++cc) pp += qr[cc] * mr[cc];
    zred[j * 8 + grp] = pp;
  }
  __syncthreads();
  if (tid < 32) {
    float t = 0.f;
#pragma unroll
    for (int gg = 0; gg < 8; ++gg) t += zred[tid * 8 + gg];
    zred[256 + tid] = t * (1.0f / 131072.0f);
  }
  __syncthreads();
  if (tid < 128) {
    const float* q2 = ws + 4096 + tid * 32;
    float kk = 0.f;
#pragma unroll 8
    for (int j = 0; j < 32; ++j) kk += q2[j] * zred[256 + j];
    kls[tid] = kk;
  }

  f32x4 acc1[2][2];
#pragma unroll
  for (int a = 0; a < 2; ++a)
#pragma unroll
    for (int b = 0; b < 2; ++b) acc1[a][b] = (f32x4){0.f, 0.f, 0.f, 0.f};

#pragma unroll
  for (int ph = 0; ph < 2; ++ph) {
#pragma unroll
    for (int k = 0; k < 8; ++k) {
      int f = k * 256 + tid, c = f >> 5, n4 = f & 31;
      int u = n4 ^ ((c >> 2) & 6);
      uint4 pk;
      pk.x = pack_hilo(xr[k].x); pk.y = pack_hilo(xr[k].y);
      pk.z = pack_hilo(xr[k].z); pk.w = pack_hilo(xr[k].w);
      *(uint4*)&xs[c * 128 + u * 4] = pk;
    }
    __syncthreads();
    if (ph == 0) {
#pragma unroll
      for (int k = 0; k < 8; ++k) {
        int f = k * 256 + tid, c = f >> 5, n4 = f & 31;
        xr[k] = *(const float4*)(xblk + (size_t)(64 + c) * CHUNKF + n4 * 4);
      }
    }
#pragma unroll
    for (int kl = 0; kl < 2; ++kl) {
#pragma unroll
      for (int nt = 0; nt < 2; ++nt) {
        const int n = wv * 32 + nt * 16 + ln;
        const int base = (kl * 32 + g * 8) * 128;
        const int u = ((n >> 2) ^ (((kl * 32 + g * 8) >> 2) & 6)) * 4 + (n & 3);
        uint q0 = xs[base + 0 * 128 + u], q1 = xs[base + 1 * 128 + u];
        uint q2 = xs[base + 2 * 128 + u], q3 = xs[base + 3 * 128 + u];
        uint q4 = xs[base + 4 * 128 + u], q5 = xs[base + 5 * 128 + u];
        uint q6 = xs[base + 6 * 128 + u], q7 = xs[base + 7 * 128 + u];
        uint4 H, L;
        H.x = (q0 & 0xffffu) | (q1 << 16);  H.y = (q2 & 0xffffu) | (q3 << 16);
        H.z = (q4 & 0xffffu) | (q5 << 16);  H.w = (q6 & 0xffffu) | (q7 << 16);
        L.x = (q0 >> 16) | (q1 & 0xffff0000u); L.y = (q2 >> 16) | (q3 & 0xffff0000u);
        L.z = (q4 >> 16) | (q5 & 0xffff0000u); L.w = (q6 >> 16) | (q7 & 0xffff0000u);
        s16x8 Bh = __builtin_bit_cast(s16x8, H);
        s16x8 Bl = __builtin_bit_cast(s16x8, L);
#pragma unroll
        for (int jt = 0; jt < 2; ++jt) {
          acc1[jt][nt] = __builtin_amdgcn_mfma_f32_16x16x32_bf16(A1[jt][ph * 2 + kl], Bh, acc1[jt][nt], 0, 0, 0);
          acc1[jt][nt] = __builtin_amdgcn_mfma_f32_16x16x32_bf16(A1[jt][ph * 2 + kl], Bl, acc1[jt][nt], 0, 0, 0);
        }
      }
    }
    __syncthreads();
  }

  uint* zw = xs + wv * 1024;
#pragma unroll
  for (int jt = 0; jt < 2; ++jt)
#pragma unroll
    for (int nt = 0; nt < 2; ++nt) {
      int n = nt * 16 + ln;
      int u = (jt * 4 + g) ^ (n & 7);
      uint4 pk;
      pk.x = pack_hilo(acc1[jt][nt][0]);
      pk.y = pack_hilo(acc1[jt][nt][1]);
      pk.z = pack_hilo(acc1[jt][nt][2]);
      pk.w = pack_hilo(acc1[jt][nt][3]);
      *(uint4*)&zw[n * 32 + u * 4] = pk;
    }

  s16x8 Ah[2], Al[2];
#pragma unroll
  for (int mt = 0; mt < 2; ++mt) {
    int n = mt * 16 + ln;
    int u0 = (2 * g) ^ (n & 7);
    int u1 = (2 * g + 1) ^ (n & 7);
    uint4 qa = *(const uint4*)&zw[n * 32 + u0 * 4];
    uint4 qb = *(const uint4*)&zw[n * 32 + u1 * 4];
    uint4 H, L;
    H.x = (qa.x & 0xffffu) | (qa.y << 16);  H.y = (qa.z & 0xffffu) | (qa.w << 16);
    H.z = (qb.x & 0xffffu) | (qb.y << 16);  H.w = (qb.z & 0xffffu) | (qb.w << 16);
    L.x = (qa.x >> 16) | (qa.y & 0xffff0000u); L.y = (qa.z >> 16) | (qa.w & 0xffff0000u);
    L.z = (qb.x >> 16) | (qb.y & 0xffff0000u); L.w = (qb.z >> 16) | (qb.w & 0xffff0000u);
    Ah[mt] = __builtin_bit_cast(s16x8, H);
    Al[mt] = __builtin_bit_cast(s16x8, L);
  }

  const size_t outbase = (size_t)nb * CIN * CHUNKF + (size_t)(hw0 + wv) * 32;
#pragma unroll 1
  for (int h = 0; h < 2; ++h) {
    s16x8 B2[4];
#pragma unroll
    for (int q = 0; q < 4; ++q)
      B2[q] = *(const s16x8*)(qw2bf + ((h * 4 + q) * 16 + ln) * 32 + g * 8);
    f32x4 acc2[4][2];
#pragma unroll
    for (int a = 0; a < 4; ++a)
#pragma unroll
      for (int b = 0; b < 2; ++b) acc2[a][b] = (f32x4){0.f, 0.f, 0.f, 0.f};
#pragma unroll
    for (int mt = 0; mt < 2; ++mt)
#pragma unroll
      for (int q = 0; q < 4; ++q) {
        acc2[q][mt] = __builtin_amdgcn_mfma_f32_16x16x32_bf16(Ah[mt], B2[q], acc2[q][mt], 0, 0, 0);
        acc2[q][mt] = __builtin_amdgcn_mfma_f32_16x16x32_bf16(Al[mt], B2[q], acc2[q][mt], 0, 0, 0);
      }
#pragma unroll
    for (int q = 0; q < 4; ++q) {
      const int nt = h * 4 + q;
      float c0[2], c1[2], c2[2], c3[2], base[2], Qi0 = 0.f;
#pragma unroll
      for (int mt = 0; mt < 2; ++mt) {
        c0[mt] = acc2[q][mt][0];
        c1[mt] = c0[mt] + acc2[q][mt][1];
        c2[mt] = c1[mt] + acc2[q][mt][2];
        c3[mt] = c2[mt] + acc2[q][mt][3];
        float Qi = c3[mt];
        float t1 = __shfl_up(Qi, 16); if (g >= 1) Qi += t1;
        float t2 = __shfl_up(Qi, 32); if (g >= 2) Qi += t2;
        base[mt] = Qi - c3[mt];
        if (mt == 0) Qi0 = Qi;
      }
      float S0tot = __shfl(Qi0, 48 + ln);
      base[1] += S0tot;
      const float kpp = kls[nt * 16 + ln];
      float* op = out + outbase + (size_t)(nt * 16 + ln) * CHUNKF;
#pragma unroll
      for (int mt = 0; mt < 2; ++mt) {
        float Bv = base[mt] - kpp;
        float prev = fminf(fmaxf(Bv, -6.f), 6.f);
        if (mt == 0 && g == 0) prev = 0.f;
        float A0 = fminf(fmaxf(Bv + c0[mt], -6.f), 6.f);
        float A1v = fminf(fmaxf(Bv + c1[mt], -6.f), 6.f);
        float A2v = fminf(fmaxf(Bv + c2[mt], -6.f), 6.f);
        float A3v = fminf(fmaxf(Bv + c3[mt], -6.f), 6.f);
        *(float4*)(op + mt * 16 + g * 4) =
            make_float4(A0 - prev, A1v - A0, A2v - A1v, A3v - A2v);
      }
    }
  }
}

extern "C" void kernel_launch(void* const* d_in, const int* in_sizes, int n_in,
                              void* d_out, int out_size, void* d_ws, size_t ws_size,
                              hipStream_t stream) {
  const float* x  = (const float*)d_in[0];
  const float* v1 = (const float*)d_in[1];
  const float* g1 = (const float*)d_in[2];
  const float* v2 = (const float*)d_in[3];
  const float* g2 = (const float*)d_in[4];
  float* ws  = (float*)d_ws;
  float* out = (float*)d_out;

  // host-side gate: all 1024 blocks must be co-resident (4 blocks/CU) for the
  // deposit/spin pattern; otherwise take the proven two-kernel path.
  int occ = 0;
  hipOccupancyMaxActiveBlocksPerMultiprocessor(&occ, fused_main, 256, 0);

  if (occ >= 4) {
    wnorm_init<<<160, 128, 0, stream>>>(v1, g1, v2, g2, ws);
    fused_main<<<1024, 256, 0, stream>>>(x, ws, out);
  } else {
    hipMemsetAsync(ws + 8192, 0, 128 * sizeof(float), stream);
    wnorm_mean_kernel<<<2208, 256, 0, stream>>>(x, v1, g1, v2, g2, ws);
    fused_kernel<<<1024, 256, 0, stream>>>(x, ws, out);
  }
}